// Round 2
// baseline (1005.706 us; speedup 1.0000x reference)
//
#include <hip/hip_runtime.h>
#include <math.h>

#define BB 4
#define TT 10
#define NN 4096
#define HH 32
#define JP 144                    // padded j (132 real: 4 b * 33 kk)
#define NJ2 (NN*JP)               // 589824
#define NH (NN*HH)                // 131072
#define NPAIR (NN*NN/2)           // 8388608 (fp16 pairs / u32 words)

typedef __attribute__((ext_vector_type(8))) short short8;
typedef __attribute__((ext_vector_type(8))) _Float16 half8;
typedef __attribute__((ext_vector_type(4))) float floatx4;
typedef __attribute__((ext_vector_type(4))) unsigned int uintx4;
typedef __attribute__((ext_vector_type(2))) unsigned int uintx2;

__device__ inline unsigned short f2h(float f) {
    _Float16 h = (_Float16)f;                  // v_cvt_f16_f32, RNE
    unsigned short u; __builtin_memcpy(&u, &h, 2);
    return u;
}
__device__ inline unsigned pk2(float a, float b) {
    return (unsigned)f2h(a) | ((unsigned)f2h(b) << 16);
}

// ---------- prep: pack A_off=spl+I, A_on=off+dtw, A9=off+masked dtw+lap, thr u8 ----------
__global__ void k_pack(const float* __restrict__ dtw, const float* __restrict__ tdl,
                       const float* __restrict__ spl, const float* __restrict__ lap,
                       unsigned* __restrict__ Aoff, unsigned* __restrict__ Aon,
                       unsigned* __restrict__ A9, unsigned short* __restrict__ thr2) {
    int e = blockIdx.x * 256 + threadIdx.x;          // pair index
    if (e >= NPAIR) return;
    size_t gi = (size_t)e * 2;
    int row = (int)(gi >> 12);
    int c0 = (int)(gi & 4095);
    float2 d = ((const float2*)dtw)[e];
    float2 td = ((const float2*)tdl)[e];
    float2 s = ((const float2*)spl)[e];
    float2 l = ((const float2*)lap)[e];
    float td0 = ceilf(fabsf(td.x)), td1 = ceilf(fabsf(td.y));
    int th0 = 10 - (int)td0; if (th0 < 0) th0 = 0;
    int th1 = 10 - (int)td1; if (th1 < 0) th1 = 0;
    float off0 = s.x + ((row == c0) ? 1.f : 0.f);
    float off1 = s.y + ((row == c0 + 1) ? 1.f : 0.f);
    float on0 = off0 + d.x, on1 = off1 + d.y;
    // t=9 mask: t+1=10 > 10-td_c  <=>  td_c>0 ; plus dtw!=0 exactness
    float a90 = off0 + l.x + ((td0 > 0.f && d.x != 0.f) ? d.x : 0.f);
    float a91 = off1 + l.y + ((td1 > 0.f && d.y != 0.f) ? d.y : 0.f);
    Aoff[e] = pk2(off0, off1);
    Aon[e]  = pk2(on0, on1);
    A9[e]   = pk2(a90, a91);
    thr2[e] = (unsigned short)(th0 | (th1 << 8));
}

// ---------- zero the pad rows j in [132,144) of Ct (ws is poisoned every launch) ----------
__global__ void k_zpad(unsigned short* __restrict__ Ct) {
    int e = blockIdx.x * 256 + threadIdx.x;          // over 10*12*4096
    if (e >= TT * 12 * NN) return;
    int n = e & 4095;
    int r = e >> 12;
    int t = r / 12, j = 132 + (r % 12);
    Ct[(size_t)(t * JP + j) * NN + n] = 0;
}

// ---------- build Ct[t][j][n] fp16, scale folded; pass1 (h raw) ----------
__global__ void k_build_ct1(const float* __restrict__ inp, const float* __restrict__ st,
                            unsigned short* __restrict__ Ct) {
    int nb = blockIdx.x, b = blockIdx.y, t = blockIdx.z;
    int tid = threadIdx.x;
    float sc = (t == TT - 1) ? (1.f / 3.f) : 0.5f;
    int kk = tid & 31;          // channel 0..31 -> j = b*33 + 1 + kk
    int ng = tid >> 5;          // 0..7
    const float* stb = st + (size_t)(t * BB + b) * NH;
    unsigned short* crow = Ct + (size_t)(t * JP + b * 33 + 1 + kk) * NN;
    int n0 = nb * 128 + ng * 16;
#pragma unroll
    for (int i = 0; i < 16; i++) {
        int n = n0 + i;
        crow[n] = f2h(stb[n * 32 + kk] * sc);       // coalesced read across kk
    }
    if (tid < 128) {            // x row: j = b*33
        int n = nb * 128 + tid;
        Ct[(size_t)(t * JP + b * 33) * NN + n] = f2h(inp[((size_t)b * TT + t) * NN + n] * sc);
    }
}

// ---------- build Ct pass2: h replaced by r*h, r = sigmoid(gcn1 flat) ----------
__global__ void k_build_ct2(const float* __restrict__ inp, const float* __restrict__ st,
                            const float* __restrict__ G, unsigned short* __restrict__ Ct) {
    int nb = blockIdx.x, b = blockIdx.y, t = blockIdx.z;
    int tid = threadIdx.x;
    float sc = (t == TT - 1) ? (1.f / 3.f) : 0.5f;
    int kk = tid & 31;
    int ng = tid >> 5;
    const float* stb = st + (size_t)(t * BB + b) * NH;
    const float* Gb = G + (size_t)(t * BB + b) * NN * 64;   // flat index == jj
    unsigned short* crow = Ct + (size_t)(t * JP + b * 33 + 1 + kk) * NN;
    int n0 = nb * 128 + ng * 16;
#pragma unroll
    for (int i = 0; i < 16; i++) {
        int n = n0 + i;
        int jj = n * 32 + kk;
        float g = Gb[jj];
        float r = 1.0f / (1.0f + expf(-g));
        crow[n] = f2h(r * stb[jj] * sc);
    }
    if (tid < 128) {
        int n = nb * 128 + tid;
        Ct[(size_t)(t * JP + b * 33) * NN + n] = f2h(inp[((size_t)b * TT + t) * NN + n] * sc);
    }
}

// ---------- MFMA GEMM: Out[ks][t][m][j] = sum_{k in split} A_t[m,k] * C_t[k,j] ----------
// v3: LDS-FREE. Both MFMA operands are contiguous 16B/lane in global:
//   A frag (16x16x32): lane holds A[row=lm][k=q*8..q*8+7] -> one dwordx4 from row-major A.
//   B frag:            lane holds B[k=q*8..][col=lm]; Ct is stored [j][k] (= C^T) -> one dwordx4.
// No staging, no barriers, no bank conflicts; per-t select done in registers.
// C-reuse across the 4 waves of a block is served by L1; A rows are wave-private.
__global__ __launch_bounds__(256, 3) void k_mfma(const unsigned* __restrict__ Aoff,
                                                 const unsigned* __restrict__ Aon,
                                                 const unsigned* __restrict__ A9,
                                                 const unsigned short* __restrict__ thr2,
                                                 const unsigned* __restrict__ Ct,
                                                 float* __restrict__ Out) {
    int t = blockIdx.z;
    int ks = blockIdx.y;
    int m0 = blockIdx.x * 128;
    int tid = threadIdx.x;
    int w = tid >> 6, lane = tid & 63;
    int lm = lane & 15, q = lane >> 4;

    floatx4 acc[2][9];
#pragma unroll
    for (int i = 0; i < 2; i++)
#pragma unroll
        for (int j = 0; j < 9; j++) acc[i][j] = (floatx4){0.f, 0.f, 0.f, 0.f};

    // per-lane word (u32) offsets
    const size_t kbase = (size_t)ks * 1024;                       // k-split col base (u32)
    const size_t gA0 = (size_t)(m0 + w * 32 + lm) * 2048 + kbase + q * 4;
    const size_t gA1 = gA0 + (size_t)16 * 2048;
    const unsigned* Cb = Ct + ((size_t)t * JP + lm) * 2048 + kbase + q * 4;

    if (t == TT - 1) {
#pragma unroll 2
        for (int kb = 0; kb < 64; kb++) {
            const int kc = kb * 16;
            half8 a0 = __builtin_bit_cast(half8, *(const uintx4*)(A9 + gA0 + kc));
            half8 a1 = __builtin_bit_cast(half8, *(const uintx4*)(A9 + gA1 + kc));
#pragma unroll
            for (int jt = 0; jt < 9; jt++) {
                half8 bh = __builtin_bit_cast(half8,
                    *(const uintx4*)(Cb + (size_t)jt * 16 * 2048 + kc));
                acc[0][jt] = __builtin_amdgcn_mfma_f32_16x16x32_f16(a0, bh, acc[0][jt], 0, 0, 0);
                acc[1][jt] = __builtin_amdgcn_mfma_f32_16x16x32_f16(a1, bh, acc[1][jt], 0, 0, 0);
            }
        }
    } else {
#pragma unroll 2
        for (int kb = 0; kb < 64; kb++) {
            const int kc = kb * 16;
            uintx4 o0 = *(const uintx4*)(Aoff + gA0 + kc);
            uintx4 n0 = *(const uintx4*)(Aon  + gA0 + kc);
            uintx2 h0 = *(const uintx2*)(thr2 + gA0 + kc);
            uintx4 o1 = *(const uintx4*)(Aoff + gA1 + kc);
            uintx4 n1 = *(const uintx4*)(Aon  + gA1 + kc);
            uintx2 h1 = *(const uintx2*)(thr2 + gA1 + kc);
            uintx4 r0, r1;
#pragma unroll
            for (int u = 0; u < 4; u++) {
                unsigned th = ((u < 2) ? h0[0] : h0[1]) >> ((u & 1) * 16);
                unsigned lo = ((int)(th & 255u) <= t) ? n0[u] : o0[u];
                unsigned hi = ((int)((th >> 8) & 255u) <= t) ? n0[u] : o0[u];
                r0[u] = (lo & 0xFFFFu) | (hi & 0xFFFF0000u);
            }
#pragma unroll
            for (int u = 0; u < 4; u++) {
                unsigned th = ((u < 2) ? h1[0] : h1[1]) >> ((u & 1) * 16);
                unsigned lo = ((int)(th & 255u) <= t) ? n1[u] : o1[u];
                unsigned hi = ((int)((th >> 8) & 255u) <= t) ? n1[u] : o1[u];
                r1[u] = (lo & 0xFFFFu) | (hi & 0xFFFF0000u);
            }
            half8 a0 = __builtin_bit_cast(half8, r0);
            half8 a1 = __builtin_bit_cast(half8, r1);
#pragma unroll
            for (int jt = 0; jt < 9; jt++) {
                half8 bh = __builtin_bit_cast(half8,
                    *(const uintx4*)(Cb + (size_t)jt * 16 * 2048 + kc));
                acc[0][jt] = __builtin_amdgcn_mfma_f32_16x16x32_f16(a0, bh, acc[0][jt], 0, 0, 0);
                acc[1][jt] = __builtin_amdgcn_mfma_f32_16x16x32_f16(a1, bh, acc[1][jt], 0, 0, 0);
            }
        }
    }
    // ---- epilogue: C/D layout col=lane&15, row=(lane>>4)*4+r
    float* Ob = Out + ((size_t)ks * TT + t) * (size_t)NN * JP;
#pragma unroll
    for (int mt = 0; mt < 2; mt++) {
        int row = m0 + w * 32 + mt * 16 + q * 4;
#pragma unroll
        for (int jt = 0; jt < 9; jt++) {
            int col = jt * 16 + lm;
#pragma unroll
            for (int r = 0; r < 4; r++)
                Ob[(size_t)(row + r) * JP + col] = acc[mt][jt][r];
        }
    }
}

// ---------- prefix sum over t (reads both k-splits, writes prefix into O0) ----------
__global__ void k_prefix(float* __restrict__ O0, const float* __restrict__ O1) {
    int e = blockIdx.x * 256 + threadIdx.x;
    if (e >= NJ2) return;
    float run = 0.f;
#pragma unroll
    for (int t = 0; t < TT; t++) {
        run += O0[(size_t)t * NJ2 + e] + O1[(size_t)t * NJ2 + e];
        O0[(size_t)t * NJ2 + e] = run;
    }
}

// ---------- gcn1[t][b][m][q] = (t+1)*b1[q] + sum_kk P[t][m][b*33+kk]*W1[kk][q] ----------
__global__ __launch_bounds__(256) void k_gcn1(const float* __restrict__ P,
                                              const float* __restrict__ W1,
                                              const float* __restrict__ b1,
                                              float* __restrict__ G) {
    int m0 = blockIdx.x * 32;
    int b = blockIdx.y, t = blockIdx.z;
    int tid = threadIdx.x;
    __shared__ float Ws[33 * 64];
    __shared__ float Ps[32 * 33];
    for (int l = tid; l < 33 * 64; l += 256) Ws[l] = W1[l];
    for (int l = tid; l < 32 * 33; l += 256) {
        int mr = l / 33, kk = l - mr * 33;
        Ps[l] = P[(size_t)(t * NN + m0 + mr) * JP + b * 33 + kk];
    }
    __syncthreads();
    int qq = tid & 63, ms = tid >> 6;
    float bias = (float)(t + 1) * b1[qq];
    for (int mi = 0; mi < 8; mi++) {
        int ml = ms * 8 + mi;
        float a = bias;
#pragma unroll
        for (int kk = 0; kk < 33; kk++) a = fmaf(Ps[ml * 33 + kk], Ws[kk * 64 + qq], a);
        G[(size_t)((t * BB + b) * NN + m0 + ml) * 64 + qq] = a;
    }
}

// ---------- reduce over t (both splits) -> S[m][JP] ----------
__global__ void k_reduce(const float* __restrict__ O0, const float* __restrict__ O1,
                         float* __restrict__ S) {
    int e = blockIdx.x * 256 + threadIdx.x;
    if (e >= NJ2) return;
    float s = 0.f;
#pragma unroll
    for (int t = 0; t < TT; t++)
        s += O0[(size_t)t * NJ2 + e] + O1[(size_t)t * NJ2 + e];
    S[e] = s;
}

// ---------- epilogue: gcn2@W2 + bias, tanh, u-gate ----------
__global__ __launch_bounds__(256) void k_final(const float* __restrict__ S,
                                               const float* __restrict__ G,
                                               const float* __restrict__ st,
                                               const float* __restrict__ W2,
                                               const float* __restrict__ b2,
                                               float* __restrict__ out) {
    __shared__ float Ws[33 * 32];
    int tid = threadIdx.x;
    for (int l = tid; l < 33 * 32; l += 256) Ws[l] = W2[l];
    __syncthreads();
    int e = blockIdx.x * 256 + tid;        // over B*N*H
    int b = e >> 17;
    int jj = e & (NH - 1);
    int m = jj >> 5, q = jj & 31;
    float a = 10.0f * b2[q];
#pragma unroll
    for (int kk = 0; kk < 33; kk++) a = fmaf(S[m * JP + b * 33 + kk], Ws[kk * 32 + q], a);
    float c = tanhf(a);
    float gu = G[(size_t)((9 * BB + b) * NN + 2048 + (jj >> 6)) * 64 + (jj & 63)];
    float u = 1.0f / (1.0f + expf(-gu));
    float h = st[(size_t)(9 * BB + b) * NH + jj];
    out[e] = u * h + (1.0f - u) * c;
}

extern "C" void kernel_launch(void* const* d_in, const int* in_sizes, int n_in,
                              void* d_out, int out_size, void* d_ws, size_t ws_size,
                              hipStream_t stream) {
    const float* inp = (const float*)d_in[0];
    const float* st  = (const float*)d_in[1];
    const float* dtw = (const float*)d_in[2];
    const float* spl = (const float*)d_in[3];
    const float* lap = (const float*)d_in[4];
    const float* tdl = (const float*)d_in[5];
    const float* W1  = (const float*)d_in[6];
    const float* b1  = (const float*)d_in[7];
    const float* W2  = (const float*)d_in[8];
    const float* b2  = (const float*)d_in[9];
    float* out = (float*)d_out;

    char* W = (char*)d_ws;
    unsigned*       Aoff = (unsigned*)W;                     W += (size_t)NPAIR * 4;
    unsigned*       Aon  = (unsigned*)W;                     W += (size_t)NPAIR * 4;
    unsigned*       A9   = (unsigned*)W;                     W += (size_t)NPAIR * 4;
    unsigned short* thr2 = (unsigned short*)W;               W += (size_t)NPAIR * 2;
    unsigned short* Ct   = (unsigned short*)W;               W += (size_t)TT * JP * NN * 2;
    float*          O    = (float*)W;                        W += (size_t)2 * TT * NJ2 * 4;
    float*          G    = (float*)W;                        W += (size_t)TT * BB * NN * 64 * 4;
    float*          S    = (float*)W;                        W += (size_t)NJ2 * 4;
    float* O1 = O + (size_t)TT * NJ2;

    k_pack<<<NPAIR / 256, 256, 0, stream>>>(dtw, tdl, spl, lap, Aoff, Aon, A9, thr2);
    k_zpad<<<(TT * 12 * NN + 255) / 256, 256, 0, stream>>>(Ct);

    dim3 gbld(NN / 128, BB, TT);
    k_build_ct1<<<gbld, 256, 0, stream>>>(inp, st, Ct);

    dim3 gmm(NN / 128, 2, TT);
    k_mfma<<<gmm, 256, 0, stream>>>(Aoff, Aon, A9, thr2, (const unsigned*)Ct, O);   // pass 1

    k_prefix<<<NJ2 / 256, 256, 0, stream>>>(O, O1);

    dim3 ggcn(NN / 32, BB, TT);
    k_gcn1<<<ggcn, 256, 0, stream>>>(O, W1, b1, G);

    k_build_ct2<<<gbld, 256, 0, stream>>>(inp, st, G, Ct);

    k_mfma<<<gmm, 256, 0, stream>>>(Aoff, Aon, A9, thr2, (const unsigned*)Ct, O);   // pass 2

    k_reduce<<<NJ2 / 256, 256, 0, stream>>>(O, O1, S);

    k_final<<<(BB * NN * HH) / 256, 256, 0, stream>>>(S, G, st, W2, b2, out);
}

// Round 3
// 671.029 us; speedup vs baseline: 1.4988x; 1.4988x over previous
//
#include <hip/hip_runtime.h>
#include <math.h>

#define BB 4
#define TT 10
#define NN 4096
#define HH 32
#define JP 144                    // padded j (132 real: 4 b * 33 kk)
#define NJ2 (NN*JP)               // 589824
#define NH (NN*HH)                // 131072
#define NPAIR (NN*NN/2)           // 8388608 (fp16 pairs / u32 words)

typedef __attribute__((ext_vector_type(8))) short short8;
typedef __attribute__((ext_vector_type(8))) _Float16 half8;
typedef __attribute__((ext_vector_type(4))) float floatx4;
typedef __attribute__((ext_vector_type(4))) unsigned int uintx4;
typedef __attribute__((ext_vector_type(2))) unsigned int uintx2;

__device__ inline unsigned short f2h(float f) {
    _Float16 h = (_Float16)f;                  // v_cvt_f16_f32, RNE
    unsigned short u; __builtin_memcpy(&u, &h, 2);
    return u;
}
__device__ inline unsigned pk2(float a, float b) {
    return (unsigned)f2h(a) | ((unsigned)f2h(b) << 16);
}

// ---------- prep: pack A_off=spl+I, A_on=off+dtw, A9=off+masked dtw+lap, thr u8 ----------
__global__ void k_pack(const float* __restrict__ dtw, const float* __restrict__ tdl,
                       const float* __restrict__ spl, const float* __restrict__ lap,
                       unsigned* __restrict__ Aoff, unsigned* __restrict__ Aon,
                       unsigned* __restrict__ A9, unsigned short* __restrict__ thr2) {
    int e = blockIdx.x * 256 + threadIdx.x;          // pair index
    if (e >= NPAIR) return;
    size_t gi = (size_t)e * 2;
    int row = (int)(gi >> 12);
    int c0 = (int)(gi & 4095);
    float2 d = ((const float2*)dtw)[e];
    float2 td = ((const float2*)tdl)[e];
    float2 s = ((const float2*)spl)[e];
    float2 l = ((const float2*)lap)[e];
    float td0 = ceilf(fabsf(td.x)), td1 = ceilf(fabsf(td.y));
    int th0 = 10 - (int)td0; if (th0 < 0) th0 = 0;
    int th1 = 10 - (int)td1; if (th1 < 0) th1 = 0;
    float off0 = s.x + ((row == c0) ? 1.f : 0.f);
    float off1 = s.y + ((row == c0 + 1) ? 1.f : 0.f);
    float on0 = off0 + d.x, on1 = off1 + d.y;
    // t=9 mask: t+1=10 > 10-td_c  <=>  td_c>0 ; plus dtw!=0 exactness
    float a90 = off0 + l.x + ((td0 > 0.f && d.x != 0.f) ? d.x : 0.f);
    float a91 = off1 + l.y + ((td1 > 0.f && d.y != 0.f) ? d.y : 0.f);
    Aoff[e] = pk2(off0, off1);
    Aon[e]  = pk2(on0, on1);
    A9[e]   = pk2(a90, a91);
    thr2[e] = (unsigned short)(th0 | (th1 << 8));
}

// ---------- build Ct[t][j][n] fp16, scale folded; pass1 (h raw) + zero pad rows ----------
__global__ void k_build_ct1(const float* __restrict__ inp, const float* __restrict__ st,
                            unsigned short* __restrict__ Ct) {
    int nb = blockIdx.x, b = blockIdx.y, t = blockIdx.z;
    int tid = threadIdx.x;
    float sc = (t == TT - 1) ? (1.f / 3.f) : 0.5f;
    int kk = tid & 31;          // channel 0..31 -> j = b*33 + 1 + kk
    int ng = tid >> 5;          // 0..7
    const float* stb = st + (size_t)(t * BB + b) * NH;
    unsigned short* crow = Ct + (size_t)(t * JP + b * 33 + 1 + kk) * NN;
    int n0 = nb * 128 + ng * 16;
#pragma unroll
    for (int i = 0; i < 16; i++) {
        int n = n0 + i;
        crow[n] = f2h(stb[n * 32 + kk] * sc);       // coalesced read across kk
    }
    if (tid < 128) {            // x row: j = b*33
        int n = nb * 128 + tid;
        Ct[(size_t)(t * JP + b * 33) * NN + n] = f2h(inp[((size_t)b * TT + t) * NN + n] * sc);
    }
    if (b == 0) {               // fused zpad: rows j in [132,144) for this (t, n-block)
        for (int l = tid; l < 12 * 128; l += 256) {
            int j = 132 + (l >> 7);
            int n = nb * 128 + (l & 127);
            Ct[(size_t)(t * JP + j) * NN + n] = 0;
        }
    }
}

// ---------- build Ct pass2: h replaced by r*h, r = sigmoid(gcn1 flat) ----------
__global__ void k_build_ct2(const float* __restrict__ inp, const float* __restrict__ st,
                            const float* __restrict__ G, unsigned short* __restrict__ Ct) {
    int nb = blockIdx.x, b = blockIdx.y, t = blockIdx.z;
    int tid = threadIdx.x;
    float sc = (t == TT - 1) ? (1.f / 3.f) : 0.5f;
    int kk = tid & 31;
    int ng = tid >> 5;
    const float* stb = st + (size_t)(t * BB + b) * NH;
    const float* Gb = G + (size_t)(t * BB + b) * NN * 64;   // flat index == jj
    unsigned short* crow = Ct + (size_t)(t * JP + b * 33 + 1 + kk) * NN;
    int n0 = nb * 128 + ng * 16;
#pragma unroll
    for (int i = 0; i < 16; i++) {
        int n = n0 + i;
        int jj = n * 32 + kk;
        float g = Gb[jj];
        float r = 1.0f / (1.0f + expf(-g));
        crow[n] = f2h(r * stb[jj] * sc);
    }
    if (tid < 128) {
        int n = nb * 128 + tid;
        Ct[(size_t)(t * JP + b * 33) * NN + n] = f2h(inp[((size_t)b * TT + t) * NN + n] * sc);
    }
}

// ---------- MFMA GEMM: Out[ks][t][m][j] = sum_{k in split} A_t[m,k] * C_t[k,j] ----------
// v4: 64-row blocks -> grid 1280 (5 blocks/CU all-resident, ~62% occupancy for latency
// hiding; v2's 640-block grid capped occupancy at 20%). Single-buffer LDS (16.6 KB),
// 2 raw barriers/step, register prefetch keeps global loads in flight across barriers
// (lgkmcnt-only waits; never drain vmcnt in the loop).
__global__ __launch_bounds__(256) void k_mfma(const unsigned* __restrict__ Aoff,
                                              const unsigned* __restrict__ Aon,
                                              const unsigned* __restrict__ A9,
                                              const unsigned short* __restrict__ thr2,
                                              const unsigned* __restrict__ Ct,
                                              float* __restrict__ Out) {
    int t = blockIdx.z;
    int ks = blockIdx.y;
    int m0 = blockIdx.x * 64;
    int tid = threadIdx.x;
    int w = tid >> 6, lane = tid & 63;
    int lm = lane & 15, q = lane >> 4;

    __shared__ short As[64 * 40];      // row stride 40 shorts (80B)
    __shared__ short Cs[JP * 40];
    unsigned* Asu = (unsigned*)As;
    unsigned* Csu = (unsigned*)Cs;

    floatx4 acc[9];
#pragma unroll
    for (int j = 0; j < 9; j++) acc[j] = (floatx4){0.f, 0.f, 0.f, 0.f};

    const bool last = (t == TT - 1);

    // staging geometry: A = 64 rows x 16 u32 -> 256 uint4, 1/thread
    //                   C = 144 rows x 16 u32 -> 576 uint4, 2/thread (+1 for wave 0)
    const int arow = tid >> 2;               // 0..63
    const int ac = (tid & 3) * 4;            // u32 col within row-chunk of 16
    const size_t kbase = (size_t)ks * 1024;  // u32 col base of this k-split
    const size_t ga = (size_t)(m0 + arow) * 2048 + kbase + ac;
    const int cj0 = arow;                    // 0..63
    const int cj1 = arow + 64;               // 64..127
    const int cj2 = arow + 128;              // 128..143 (wave 0 only)
    const unsigned* CtT = Ct + (size_t)t * JP * 2048 + kbase + ac;

    // prefetch registers (loaded at step i, staged to LDS at step i+1)
    uintx4 pO, pA, rC0, rC1, rC2;
    uintx2 pT;

    auto LOADS = [&](int ku) {               // ku = u32 col offset within split
        if (last) {
            pO = *(const uintx4*)(A9 + ga + ku);
        } else {
            pO = *(const uintx4*)(Aoff + ga + ku);
            pA = *(const uintx4*)(Aon  + ga + ku);
            pT = *(const uintx2*)(thr2 + ga + ku);
        }
        rC0 = *(const uintx4*)(CtT + (size_t)cj0 * 2048 + ku);
        rC1 = *(const uintx4*)(CtT + (size_t)cj1 * 2048 + ku);
        if (tid < 64) rC2 = *(const uintx4*)(CtT + (size_t)cj2 * 2048 + ku);
    };

    LOADS(0);                                // prologue: step 0 data
    for (int kb = 0; kb < 64; kb++) {
        if (kb) __builtin_amdgcn_s_barrier();    // prev step's reads all done
        // ---- write phase: select + stage into LDS (regs from step kb)
        uintx4 r;
        if (last) {
            r = pO;
        } else {
#pragma unroll
            for (int u = 0; u < 4; u++) {
                unsigned th = ((u < 2) ? pT[0] : pT[1]) >> ((u & 1) * 16);
                unsigned lo = ((int)(th & 255u) <= t) ? pA[u] : pO[u];
                unsigned hi = ((int)((th >> 8) & 255u) <= t) ? pA[u] : pO[u];
                r[u] = (lo & 0xFFFFu) | (hi & 0xFFFF0000u);
            }
        }
        *(uintx4*)(Asu + arow * 20 + ac) = r;
        *(uintx4*)(Csu + cj0 * 20 + ac) = rC0;
        *(uintx4*)(Csu + cj1 * 20 + ac) = rC1;
        if (tid < 64) *(uintx4*)(Csu + cj2 * 20 + ac) = rC2;
        // ---- issue next step's global loads; stay in flight across the barrier
        if (kb < 63) LOADS((kb + 1) * 16);
        // ---- wait own LDS writes only (NOT vmcnt), then barrier
        asm volatile("s_waitcnt lgkmcnt(0)" ::: "memory");
        __builtin_amdgcn_s_barrier();
        asm volatile("" ::: "memory");
        // ---- compute phase: fragments + MFMA; wave w owns rows [w*16, w*16+16)
        short8 av = *(const short8*)(As + (w * 16 + lm) * 40 + q * 8);
        half8 ah = __builtin_bit_cast(half8, av);
#pragma unroll
        for (int jt = 0; jt < 9; jt++) {
            short8 bv = *(const short8*)(Cs + (jt * 16 + lm) * 40 + q * 8);
            half8 bh = __builtin_bit_cast(half8, bv);
            acc[jt] = __builtin_amdgcn_mfma_f32_16x16x32_f16(ah, bh, acc[jt], 0, 0, 0);
        }
        // NOTE: all ds_reads complete before each MFMA issues (compiler lgkm waits),
        // so reaching the top-of-loop barrier implies this wave's reads are done.
    }
    // ---- epilogue: C/D layout col=lane&15, row=(lane>>4)*4+r
    float* Ob = Out + ((size_t)ks * TT + t) * (size_t)NN * JP;
    int row = m0 + w * 16 + q * 4;
#pragma unroll
    for (int jt = 0; jt < 9; jt++) {
        int col = jt * 16 + lm;
#pragma unroll
        for (int r = 0; r < 4; r++)
            Ob[(size_t)(row + r) * JP + col] = acc[jt][r];
    }
}

// ---------- prefix sum over t (both k-splits); writes prefix into O0 and total into S ----------
__global__ void k_prefix(float* __restrict__ O0, const float* __restrict__ O1,
                         float* __restrict__ S) {
    int e = blockIdx.x * 256 + threadIdx.x;
    if (e >= NJ2) return;
    float run = 0.f;
#pragma unroll
    for (int t = 0; t < TT; t++) {
        run += O0[(size_t)t * NJ2 + e] + O1[(size_t)t * NJ2 + e];
        O0[(size_t)t * NJ2 + e] = run;
    }
    S[e] = run;                          // fused k_reduce: total == prefix at t=9
}

// ---------- gcn1[t][b][m][q] = (t+1)*b1[q] + sum_kk P[t][m][b*33+kk]*W1[kk][q] ----------
__global__ __launch_bounds__(256) void k_gcn1(const float* __restrict__ P,
                                              const float* __restrict__ W1,
                                              const float* __restrict__ b1,
                                              float* __restrict__ G) {
    int m0 = blockIdx.x * 32;
    int b = blockIdx.y, t = blockIdx.z;
    int tid = threadIdx.x;
    __shared__ float Ws[33 * 64];
    __shared__ float Ps[32 * 33];
    for (int l = tid; l < 33 * 64; l += 256) Ws[l] = W1[l];
    for (int l = tid; l < 32 * 33; l += 256) {
        int mr = l / 33, kk = l - mr * 33;
        Ps[l] = P[(size_t)(t * NN + m0 + mr) * JP + b * 33 + kk];
    }
    __syncthreads();
    int qq = tid & 63, ms = tid >> 6;
    float bias = (float)(t + 1) * b1[qq];
    for (int mi = 0; mi < 8; mi++) {
        int ml = ms * 8 + mi;
        float a = bias;
#pragma unroll
        for (int kk = 0; kk < 33; kk++) a = fmaf(Ps[ml * 33 + kk], Ws[kk * 64 + qq], a);
        G[(size_t)((t * BB + b) * NN + m0 + ml) * 64 + qq] = a;
    }
}

// ---------- epilogue: gcn2@W2 + bias, tanh, u-gate ----------
__global__ __launch_bounds__(256) void k_final(const float* __restrict__ S,
                                               const float* __restrict__ G,
                                               const float* __restrict__ st,
                                               const float* __restrict__ W2,
                                               const float* __restrict__ b2,
                                               float* __restrict__ out) {
    __shared__ float Ws[33 * 32];
    int tid = threadIdx.x;
    for (int l = tid; l < 33 * 32; l += 256) Ws[l] = W2[l];
    __syncthreads();
    int e = blockIdx.x * 256 + tid;        // over B*N*H
    int b = e >> 17;
    int jj = e & (NH - 1);
    int m = jj >> 5, q = jj & 31;
    float a = 10.0f * b2[q];
#pragma unroll
    for (int kk = 0; kk < 33; kk++) a = fmaf(S[m * JP + b * 33 + kk], Ws[kk * 32 + q], a);
    float c = tanhf(a);
    float gu = G[(size_t)((9 * BB + b) * NN + 2048 + (jj >> 6)) * 64 + (jj & 63)];
    float u = 1.0f / (1.0f + expf(-gu));
    float h = st[(size_t)(9 * BB + b) * NH + jj];
    out[e] = u * h + (1.0f - u) * c;
}

extern "C" void kernel_launch(void* const* d_in, const int* in_sizes, int n_in,
                              void* d_out, int out_size, void* d_ws, size_t ws_size,
                              hipStream_t stream) {
    const float* inp = (const float*)d_in[0];
    const float* st  = (const float*)d_in[1];
    const float* dtw = (const float*)d_in[2];
    const float* spl = (const float*)d_in[3];
    const float* lap = (const float*)d_in[4];
    const float* tdl = (const float*)d_in[5];
    const float* W1  = (const float*)d_in[6];
    const float* b1  = (const float*)d_in[7];
    const float* W2  = (const float*)d_in[8];
    const float* b2  = (const float*)d_in[9];
    float* out = (float*)d_out;

    char* W = (char*)d_ws;
    unsigned*       Aoff = (unsigned*)W;                     W += (size_t)NPAIR * 4;
    unsigned*       Aon  = (unsigned*)W;                     W += (size_t)NPAIR * 4;
    unsigned*       A9   = (unsigned*)W;                     W += (size_t)NPAIR * 4;
    unsigned short* thr2 = (unsigned short*)W;               W += (size_t)NPAIR * 2;
    unsigned short* Ct   = (unsigned short*)W;               W += (size_t)TT * JP * NN * 2;
    float*          O    = (float*)W;                        W += (size_t)2 * TT * NJ2 * 4;
    float*          G    = (float*)W;                        W += (size_t)TT * BB * NN * 64 * 4;
    float*          S    = (float*)W;                        W += (size_t)NJ2 * 4;
    float* O1 = O + (size_t)TT * NJ2;

    k_pack<<<NPAIR / 256, 256, 0, stream>>>(dtw, tdl, spl, lap, Aoff, Aon, A9, thr2);

    dim3 gbld(NN / 128, BB, TT);
    k_build_ct1<<<gbld, 256, 0, stream>>>(inp, st, Ct);

    dim3 gmm(NN / 64, 2, TT);
    k_mfma<<<gmm, 256, 0, stream>>>(Aoff, Aon, A9, thr2, (const unsigned*)Ct, O);   // pass 1

    k_prefix<<<NJ2 / 256, 256, 0, stream>>>(O, O1, S);   // S unused after pass1 prefix; cheap

    dim3 ggcn(NN / 32, BB, TT);
    k_gcn1<<<ggcn, 256, 0, stream>>>(O, W1, b1, G);

    k_build_ct2<<<gbld, 256, 0, stream>>>(inp, st, G, Ct);

    k_mfma<<<gmm, 256, 0, stream>>>(Aoff, Aon, A9, thr2, (const unsigned*)Ct, O);   // pass 2

    k_prefix<<<NJ2 / 256, 256, 0, stream>>>(O, O1, S);   // fused reduce: S = total over t

    k_final<<<(BB * NN * HH) / 256, 256, 0, stream>>>(S, G, st, W2, b2, out);
}